// Round 5
// baseline (1090.132 us; speedup 1.0000x reference)
//
#include <hip/hip_runtime.h>

#define N_NODES 100000
#define N_EDGES 1600000
#define N_GRAPHS 1024
#define D 128
#define NL 3
#define BN_EPS 1e-5f
#define BG 196                                  // dst nodes per bucket
#define NB ((N_NODES + BG - 1) / BG)            // 511 buckets
#define EPB 16384                               // edges per k_part block

typedef __attribute__((ext_vector_type(8))) short bf16x8;
typedef __attribute__((ext_vector_type(4))) float f32x4;

__device__ __forceinline__ unsigned short f2b(float f) {
    unsigned int u = __float_as_uint(f);
    u += 0x7fff + ((u >> 16) & 1);   // round to nearest even
    return (unsigned short)(u >> 16);
}
__device__ __forceinline__ float b2f(unsigned short b) {
    return __uint_as_float(((unsigned int)b) << 16);
}

// ---------------- dtype-robust index accessor ----------------
__device__ __forceinline__ int geti(const void* p, long long i, int f64) {
    return f64 ? (int)((const long long*)p)[i] : ((const int*)p)[i];
}

__global__ void k_detect(const void* ei, int* flag) {
    int t = threadIdx.x;
    const int* p = (const int*)ei;
    int acc = p[2 * t + 1] | p[2 * (t + 64) + 1];
    unsigned long long b = __ballot(acc != 0);
    if (t == 0) *flag = (b == 0ULL) ? 1 : 0;
}

// ---------------- weight prep: Wt[m][n][k] = bf16(W[m][k][n]) ----------------
__global__ void k_wprep(const float* __restrict__ W1, const float* __restrict__ W2,
                        unsigned short* __restrict__ Wt) {
    int m = blockIdx.y;
    int k = blockIdx.x;
    int n = threadIdx.x;
    const float* src = (m < NL) ? (W1 + (size_t)m * D * D) : (W2 + (size_t)(m - NL) * D * D);
    Wt[(size_t)m * D * D + n * D + k] = f2b(src[k * D + n]);
}

// ---------------- x -> bf16 mirror ----------------
__global__ void k_x2b(const float* __restrict__ x, unsigned short* __restrict__ xb) {
    int i = (blockIdx.x * 256 + threadIdx.x) * 4;
    float4 v = *(const float4*)&x[i];
    ushort4 b;
    b.x = f2b(v.x); b.y = f2b(v.y); b.z = f2b(v.z); b.w = f2b(v.w);
    *(ushort4*)&xb[i] = b;
}

// ---------------- CSR build: degree histogram ----------------
__global__ void k_hist(const void* ei, const int* __restrict__ flag, int* __restrict__ deg) {
    int e = blockIdx.x * 256 + threadIdx.x;
    int f = *flag;
    if (e < N_EDGES) {
        int d = geti(ei, (long long)N_EDGES + e, f);
        atomicAdd(&deg[d], 1);
    }
}

__global__ void k_scan1(const int* __restrict__ deg, int* __restrict__ bsum) {
    __shared__ int wsum[4];
    int tid = threadIdx.x;
    int base = blockIdx.x * 1024 + tid * 4;
    int s = 0;
#pragma unroll
    for (int j = 0; j < 4; ++j) {
        int idx = base + j;
        if (idx < N_NODES) s += deg[idx];
    }
    for (int off = 32; off > 0; off >>= 1) s += __shfl_down(s, off, 64);
    if ((tid & 63) == 0) wsum[tid >> 6] = s;
    __syncthreads();
    if (tid == 0) bsum[blockIdx.x] = wsum[0] + wsum[1] + wsum[2] + wsum[3];
}

__global__ void k_scan2(const int* __restrict__ bsum, int* __restrict__ boff,
                        int* __restrict__ rowp) {
    if (threadIdx.x == 0) {
        int run = 0;
        for (int b = 0; b < 98; ++b) {
            boff[b] = run;
            run += bsum[b];
        }
        rowp[N_NODES] = run;
    }
}

__global__ void k_scan3(const int* __restrict__ deg, const int* __restrict__ boff,
                        int* __restrict__ rowp) {
    __shared__ int wsum[4];
    int tid = threadIdx.x;
    int lane = tid & 63;
    int w = tid >> 6;
    int base = blockIdx.x * 1024 + tid * 4;
    int d[4];
    int tot = 0;
#pragma unroll
    for (int j = 0; j < 4; ++j) {
        int idx = base + j;
        d[j] = (idx < N_NODES) ? deg[idx] : 0;
        tot += d[j];
    }
    int incl = tot;
    for (int off = 1; off < 64; off <<= 1) {
        int v = __shfl_up(incl, off, 64);
        if (lane >= off) incl += v;
    }
    if (lane == 63) wsum[w] = incl;
    __syncthreads();
    int woff = boff[blockIdx.x];
    for (int w2 = 0; w2 < w; ++w2) woff += wsum[w2];
    int ex = woff + incl - tot;
#pragma unroll
    for (int j = 0; j < 4; ++j) {
        int idx = base + j;
        if (idx < N_NODES) rowp[idx] = ex;
        ex += d[j];
    }
}

// gcur[b] = rowp[b*BG]  (bucket write cursors for pass A)
__global__ void k_gcur(const int* __restrict__ rowp, int* __restrict__ gcur) {
    int b = blockIdx.x * 256 + threadIdx.x;
    if (b < NB) gcur[b] = rowp[min(b * BG, N_NODES)];
}

// ---- Pass A: partition edges into NB coarse dst-buckets, packed (dl<<17|src) ----
__global__ __launch_bounds__(256) void k_part(const void* ei, const int* __restrict__ flag,
                                              int* __restrict__ gcur,
                                              unsigned int* __restrict__ tmp) {
    __shared__ int hist[NB + 1];
    __shared__ int cur[NB + 1];
    int tid = threadIdx.x;
    long long e0 = (long long)blockIdx.x * EPB;
    int f = *flag;
    for (int b = tid; b < NB; b += 256) hist[b] = 0;
    __syncthreads();
    // phase 1: per-bucket count
    for (int i = 0; i < EPB / 256; ++i) {
        long long e = e0 + i * 256 + tid;
        if (e < N_EDGES) {
            int d = geti(ei, (long long)N_EDGES + e, f);
            atomicAdd(&hist[d / BG], 1);
        }
    }
    __syncthreads();
    // phase 2: reserve contiguous runs in each bucket's region
    for (int b = tid; b < NB; b += 256) {
        int h = hist[b];
        cur[b] = h ? atomicAdd(&gcur[b], h) : 0;
    }
    __syncthreads();
    // phase 3: write packed entries (contiguous per bucket per block)
    for (int i = 0; i < EPB / 256; ++i) {
        long long e = e0 + i * 256 + tid;
        if (e < N_EDGES) {
            int d = geti(ei, (long long)N_EDGES + e, f);
            int s = geti(ei, e, f);
            int b = d / BG;
            int pos = atomicAdd(&cur[b], 1);
            tmp[pos] = ((unsigned int)(d - b * BG) << 17) | (unsigned int)s;
        }
    }
}

// ---- Pass B: within-bucket scatter to exact CSR position (L2-local, merged) ----
__global__ __launch_bounds__(256) void k_fscat(const unsigned int* __restrict__ tmp,
                                               const int* __restrict__ rowp,
                                               int* __restrict__ eidx) {
    __shared__ int cur[BG];
    __shared__ int s_se[2];
    int b = blockIdx.x;
    int nb = b * BG;
    int nn = min(BG, N_NODES - nb);
    int tid = threadIdx.x;
    if (tid < nn) cur[tid] = rowp[nb + tid];
    if (tid == 0) s_se[0] = rowp[nb];
    if (tid == 1) s_se[1] = rowp[nb + nn];
    __syncthreads();
    for (int t = s_se[0] + tid; t < s_se[1]; t += 256) {
        unsigned int u = tmp[t];
        int dl = u >> 17;
        int pos = atomicAdd(&cur[dl], 1);
        eidx[pos] = (int)(u & 0x1FFFF);
    }
}

// -------- fused aggregation + GEMM1 + BN-stats --------
// Block: 128 rows. Phase 1: 4 waves gather/aggregate 32 nodes each straight into
// the A-tile LDS (fp32 accumulate, bf16 store). Phase 2: MFMA z = agg @ W1 + b1.
// Epilogue: store z bf16, accumulate per-feature sum/sumsq into stats.
__global__ __launch_bounds__(256) void k_fused1(const unsigned short* __restrict__ xb,
                                                const int* __restrict__ rowp,
                                                const int* __restrict__ eidx,
                                                const unsigned short* __restrict__ Wt,
                                                const float* __restrict__ bias,
                                                float* __restrict__ stats,
                                                unsigned short* __restrict__ zb) {
    __shared__ unsigned short As[128 * 136];
    __shared__ unsigned short Ws[128 * 136];
    __shared__ float red1[128];
    __shared__ float red2[128];

    int tid = threadIdx.x;
    int row0 = blockIdx.x * 128;

    if (tid < 128) {
        red1[tid] = 0.f;
        red2[tid] = 0.f;
    }

    // stage Wt (full K=128)
#pragma unroll
    for (int i = 0; i < 8; ++i) {
        int chunk = tid + 256 * i;
        int n = chunk >> 4;
        int k8 = (chunk & 15) * 8;
        *(bf16x8*)&Ws[n * 136 + k8] = *(const bf16x8*)&Wt[n * 128 + k8];
    }

    // gather + aggregate into As
    int w = tid >> 6, lane = tid & 63;
    const unsigned int* x1 = (const unsigned int*)xb;
    for (int r = w * 32; r < w * 32 + 32; ++r) {
        int node = row0 + r;
        unsigned int o = 0;
        if (node < N_NODES) {
            unsigned int u = x1[(size_t)node * 64 + lane];
            float accx = __uint_as_float(u << 16);
            float accy = __uint_as_float(u & 0xffff0000u);
            int s = rowp[node], e = rowp[node + 1];
            int i = s;
            for (; i + 7 < e; i += 8) {
                unsigned int v0 = x1[(size_t)eidx[i] * 64 + lane];
                unsigned int v1 = x1[(size_t)eidx[i + 1] * 64 + lane];
                unsigned int v2 = x1[(size_t)eidx[i + 2] * 64 + lane];
                unsigned int v3 = x1[(size_t)eidx[i + 3] * 64 + lane];
                unsigned int v4 = x1[(size_t)eidx[i + 4] * 64 + lane];
                unsigned int v5 = x1[(size_t)eidx[i + 5] * 64 + lane];
                unsigned int v6 = x1[(size_t)eidx[i + 6] * 64 + lane];
                unsigned int v7 = x1[(size_t)eidx[i + 7] * 64 + lane];
                accx += __uint_as_float(v0 << 16) + __uint_as_float(v1 << 16) +
                        __uint_as_float(v2 << 16) + __uint_as_float(v3 << 16) +
                        __uint_as_float(v4 << 16) + __uint_as_float(v5 << 16) +
                        __uint_as_float(v6 << 16) + __uint_as_float(v7 << 16);
                accy += __uint_as_float(v0 & 0xffff0000u) + __uint_as_float(v1 & 0xffff0000u) +
                        __uint_as_float(v2 & 0xffff0000u) + __uint_as_float(v3 & 0xffff0000u) +
                        __uint_as_float(v4 & 0xffff0000u) + __uint_as_float(v5 & 0xffff0000u) +
                        __uint_as_float(v6 & 0xffff0000u) + __uint_as_float(v7 & 0xffff0000u);
            }
            for (; i < e; ++i) {
                unsigned int v0 = x1[(size_t)eidx[i] * 64 + lane];
                accx += __uint_as_float(v0 << 16);
                accy += __uint_as_float(v0 & 0xffff0000u);
            }
            o = ((unsigned int)f2b(accy) << 16) | f2b(accx);
        }
        *(unsigned int*)&As[r * 136 + lane * 2] = o;
    }
    __syncthreads();

    int q = lane >> 4, ln = lane & 15;
    int rbase = (w & 1) * 64, cbase = (w >> 1) * 64;

    f32x4 acc[4][4];
    f32x4 z4 = {0.f, 0.f, 0.f, 0.f};
#pragma unroll
    for (int rt = 0; rt < 4; ++rt)
#pragma unroll
        for (int ct = 0; ct < 4; ++ct) acc[rt][ct] = z4;

#pragma unroll
    for (int ks = 0; ks < 4; ++ks) {
        bf16x8 af[4], bfr[4];
#pragma unroll
        for (int rt = 0; rt < 4; ++rt)
            af[rt] = *(bf16x8*)&As[(rbase + rt * 16 + ln) * 136 + ks * 32 + q * 8];
#pragma unroll
        for (int ct = 0; ct < 4; ++ct)
            bfr[ct] = *(bf16x8*)&Ws[(cbase + ct * 16 + ln) * 136 + ks * 32 + q * 8];
#pragma unroll
        for (int rt = 0; rt < 4; ++rt)
#pragma unroll
            for (int ct = 0; ct < 4; ++ct)
                acc[rt][ct] = __builtin_amdgcn_mfma_f32_16x16x32_bf16(af[rt], bfr[ct],
                                                                      acc[rt][ct], 0, 0, 0);
    }

    // epilogue: store z + per-feature stats
    float bsv[4], psum[4] = {0.f, 0.f, 0.f, 0.f}, psq[4] = {0.f, 0.f, 0.f, 0.f};
    int col[4];
#pragma unroll
    for (int ct = 0; ct < 4; ++ct) {
        col[ct] = cbase + ct * 16 + ln;
        bsv[ct] = bias[col[ct]];
    }
#pragma unroll
    for (int rt = 0; rt < 4; ++rt) {
        int gr0 = row0 + rbase + rt * 16 + q * 4;
#pragma unroll
        for (int i = 0; i < 4; ++i) {
            int gr = gr0 + i;
            if (gr < N_NODES) {
#pragma unroll
                for (int ct = 0; ct < 4; ++ct) {
                    float z = acc[rt][ct][i] + bsv[ct];
                    zb[(size_t)gr * 128 + col[ct]] = f2b(z);
                    psum[ct] += z;
                    psq[ct] += z * z;
                }
            }
        }
    }
#pragma unroll
    for (int ct = 0; ct < 4; ++ct) {
        atomicAdd(&red1[col[ct]], psum[ct]);
        atomicAdd(&red2[col[ct]], psq[ct]);
    }
    __syncthreads();
    if (tid < 128) {
        atomicAdd(&stats[tid], red1[tid]);
        atomicAdd(&stats[128 + tid], red2[tid]);
    }
}

// ---------------- GEMM2: x' = relu(relu(BN(z)) @ W2 + b2) (bf16 in/out) --------
__global__ __launch_bounds__(256) void k_lin2(const unsigned short* __restrict__ A,
                                              const unsigned short* __restrict__ Wt,
                                              const float* __restrict__ bias,
                                              const float* __restrict__ stats,
                                              const float* __restrict__ gamma,
                                              const float* __restrict__ beta,
                                              unsigned short* __restrict__ outb) {
    __shared__ unsigned short As[128 * 136];
    __shared__ unsigned short Ws[128 * 136];
    __shared__ float red1[128];
    __shared__ float red2[128];

    int tid = threadIdx.x;
    int row0 = blockIdx.x * 128;

    if (tid < 128) {
        float s1 = stats[tid];
        float s2 = stats[128 + tid];
        float mu = s1 / (float)N_NODES;
        float var = s2 / (float)N_NODES - mu * mu;
        float sc = rsqrtf(var + BN_EPS) * gamma[tid];
        red1[tid] = sc;
        red2[tid] = beta[tid] - mu * sc;
    }

#pragma unroll
    for (int i = 0; i < 8; ++i) {
        int chunk = tid + 256 * i;
        int n = chunk >> 4;
        int k8 = (chunk & 15) * 8;
        *(bf16x8*)&Ws[n * 136 + k8] = *(const bf16x8*)&Wt[n * 128 + k8];
    }
    __syncthreads();

#pragma unroll
    for (int i = 0; i < 8; ++i) {
        int chunk = tid + 256 * i;
        int row = chunk >> 4;
        int k8 = (chunk & 15) * 8;
        int gr = row0 + row;
        bf16x8 v = {0, 0, 0, 0, 0, 0, 0, 0};
        if (gr < N_NODES) v = *(const bf16x8*)&A[(size_t)gr * 128 + k8];
        bf16x8 o;
#pragma unroll
        for (int t = 0; t < 8; ++t) {
            float xv = b2f((unsigned short)v[t]);
            float z = fmaxf(xv * red1[k8 + t] + red2[k8 + t], 0.f);
            o[t] = (short)f2b(z);
        }
        *(bf16x8*)&As[row * 136 + k8] = o;
    }
    __syncthreads();

    int w = tid >> 6, lane = tid & 63, q = lane >> 4, ln = lane & 15;
    int rbase = (w & 1) * 64, cbase = (w >> 1) * 64;

    f32x4 acc[4][4];
    f32x4 z4 = {0.f, 0.f, 0.f, 0.f};
#pragma unroll
    for (int rt = 0; rt < 4; ++rt)
#pragma unroll
        for (int ct = 0; ct < 4; ++ct) acc[rt][ct] = z4;

#pragma unroll
    for (int ks = 0; ks < 4; ++ks) {
        bf16x8 af[4], bfr[4];
#pragma unroll
        for (int rt = 0; rt < 4; ++rt)
            af[rt] = *(bf16x8*)&As[(rbase + rt * 16 + ln) * 136 + ks * 32 + q * 8];
#pragma unroll
        for (int ct = 0; ct < 4; ++ct)
            bfr[ct] = *(bf16x8*)&Ws[(cbase + ct * 16 + ln) * 136 + ks * 32 + q * 8];
#pragma unroll
        for (int rt = 0; rt < 4; ++rt)
#pragma unroll
            for (int ct = 0; ct < 4; ++ct)
                acc[rt][ct] = __builtin_amdgcn_mfma_f32_16x16x32_bf16(af[rt], bfr[ct],
                                                                      acc[rt][ct], 0, 0, 0);
    }

    float bsv[4];
    int col[4];
#pragma unroll
    for (int ct = 0; ct < 4; ++ct) {
        col[ct] = cbase + ct * 16 + ln;
        bsv[ct] = bias[col[ct]];
    }
#pragma unroll
    for (int rt = 0; rt < 4; ++rt) {
        int gr0 = row0 + rbase + rt * 16 + q * 4;
#pragma unroll
        for (int i = 0; i < 4; ++i) {
            int gr = gr0 + i;
            if (gr < N_NODES) {
#pragma unroll
                for (int ct = 0; ct < 4; ++ct) {
                    float z = fmaxf(acc[rt][ct][i] + bsv[ct], 0.f);
                    outb[(size_t)gr * 128 + col[ct]] = f2b(z);
                }
            }
        }
    }
}

// ---------------- graph boundaries (batch is sorted) ----------------
__global__ void k_bounds(const void* batch, const int* __restrict__ flag,
                         int* __restrict__ starts) {
    int g = blockIdx.x * 256 + threadIdx.x;
    if (g > N_GRAPHS) return;
    int f = *flag;
    int lo = 0, hi = N_NODES;
    while (lo < hi) {
        int mid = (lo + hi) >> 1;
        if (geti(batch, mid, f) < g) lo = mid + 1;
        else hi = mid;
    }
    starts[g] = lo;
}

// ---------------- global add pool (bf16 in, fp32 out) ----------------
__global__ void k_pool(const unsigned short* __restrict__ xb, const int* __restrict__ starts,
                       float* __restrict__ gp) {
    int b = blockIdx.x, fi = threadIdx.x;
    int s = starts[b], e = starts[b + 1];
    float acc = 0.f;
    for (int i = s; i < e; ++i) acc += b2f(xb[(size_t)i * 128 + fi]);
    gp[(size_t)b * 128 + fi] = acc;
}

// ---------------- head MLP ----------------
__global__ void k_head(const float* __restrict__ gp, const float* __restrict__ fW1,
                       const float* __restrict__ fb1, const float* __restrict__ fW2,
                       const float* __restrict__ fb2, float* __restrict__ out) {
    __shared__ float gs[128];
    __shared__ float hs[128];
    int b = blockIdx.x, t = threadIdx.x;
    gs[t] = gp[(size_t)b * 128 + t];
    __syncthreads();
    float a = fb1[t];
    for (int k = 0; k < 128; ++k) a += gs[k] * fW1[k * 128 + t];
    hs[t] = fmaxf(a, 0.f);
    __syncthreads();
    if (t < 64) {
        float o = fb2[t];
        for (int k = 0; k < 128; ++k) o += hs[k] * fW2[k * 64 + t];
        out[(size_t)b * 64 + t] = o;
    }
}

extern "C" void kernel_launch(void* const* d_in, const int* in_sizes, int n_in,
                              void* d_out, int out_size, void* d_ws, size_t ws_size,
                              hipStream_t stream) {
    const float* x     = (const float*)d_in[0];
    const void*  ei    = d_in[1];
    const void*  batch = d_in[2];
    const float* W1    = (const float*)d_in[3];
    const float* b1    = (const float*)d_in[4];
    const float* gamma = (const float*)d_in[5];
    const float* beta  = (const float*)d_in[6];
    const float* W2    = (const float*)d_in[7];
    const float* b2    = (const float*)d_in[8];
    const float* fW1   = (const float*)d_in[9];
    const float* fb1   = (const float*)d_in[10];
    const float* fW2   = (const float*)d_in[11];
    const float* fb2   = (const float*)d_in[12];
    float* out = (float*)d_out;

    // workspace layout (all chunks multiple of 16 B)
    unsigned short* xb = (unsigned short*)d_ws;                    // 12.8M us
    unsigned short* zb = xb + (size_t)N_NODES * D;                 // 12.8M us
    int* deg    = (int*)(zb + (size_t)N_NODES * D);                // 100,000
    int* rowp   = deg + N_NODES;                                   // 100,004 (padded)
    int* eidx   = rowp + 100004;                                   // 1,600,000
    unsigned int* tmp = (unsigned int*)(eidx + N_EDGES);           // 1,600,000
    int* starts = (int*)(tmp + N_EDGES);                           // 1,028 (padded)
    int* dflag  = starts + 1028;                                   // 4
    int* bsum   = dflag + 4;                                       // 128
    int* boff   = bsum + 128;                                      // 128
    int* gcur   = boff + 128;                                      // 512
    float* stats = (float*)(gcur + 512);                           // 768
    float* gp    = stats + NL * 256;                               // 131,072
    unsigned short* Wt = (unsigned short*)(gp + (size_t)N_GRAPHS * D);  // 6*16384 us

    hipMemsetAsync(deg, 0, N_NODES * sizeof(int), stream);
    hipMemsetAsync(stats, 0, NL * 256 * sizeof(float), stream);

    k_detect<<<1, 64, 0, stream>>>(ei, dflag);
    k_wprep<<<dim3(128, 2 * NL), 128, 0, stream>>>(W1, W2, Wt);
    k_x2b<<<(N_NODES * D) / 1024, 256, 0, stream>>>(x, xb);
    k_hist<<<(N_EDGES + 255) / 256, 256, 0, stream>>>(ei, dflag, deg);
    k_scan1<<<98, 256, 0, stream>>>(deg, bsum);
    k_scan2<<<1, 64, 0, stream>>>(bsum, boff, rowp);
    k_scan3<<<98, 256, 0, stream>>>(deg, boff, rowp);
    k_gcur<<<2, 256, 0, stream>>>(rowp, gcur);
    k_part<<<(N_EDGES + EPB - 1) / EPB, 256, 0, stream>>>(ei, dflag, gcur, tmp);
    k_fscat<<<NB, 256, 0, stream>>>(tmp, rowp, eidx);

    const int gemm_grid = (N_NODES + 127) / 128;  // 782
    for (int l = 0; l < NL; ++l) {
        k_fused1<<<gemm_grid, 256, 0, stream>>>(
            xb, rowp, eidx, Wt + (size_t)l * D * D, b1 + (size_t)l * D,
            stats + (size_t)l * 256, zb);
        k_lin2<<<gemm_grid, 256, 0, stream>>>(
            zb, Wt + (size_t)(NL + l) * D * D, b2 + (size_t)l * D,
            stats + (size_t)l * 256, gamma + (size_t)l * D, beta + (size_t)l * D, xb);
    }

    k_bounds<<<5, 256, 0, stream>>>(batch, dflag, starts);
    k_pool<<<N_GRAPHS, 128, 0, stream>>>(xb, starts, gp);
    k_head<<<N_GRAPHS, 128, 0, stream>>>(gp, fW1, fb1, fW2, fb2, out);
}

// Round 6
// 714.252 us; speedup vs baseline: 1.5263x; 1.5263x over previous
//
#include <hip/hip_runtime.h>

#define N_NODES 100000
#define N_EDGES 1600000
#define N_GRAPHS 1024
#define D 128
#define NL 3
#define BN_EPS 1e-5f
#define BG 196                                  // dst nodes per bucket
#define NB ((N_NODES + BG - 1) / BG)            // 511 buckets
#define EPB 16384                               // edges per k_part block

typedef __attribute__((ext_vector_type(8))) short bf16x8;
typedef __attribute__((ext_vector_type(4))) float f32x4;

__device__ __forceinline__ unsigned short f2b(float f) {
    unsigned int u = __float_as_uint(f);
    u += 0x7fff + ((u >> 16) & 1);   // round to nearest even
    return (unsigned short)(u >> 16);
}
__device__ __forceinline__ float b2f(unsigned short b) {
    return __uint_as_float(((unsigned int)b) << 16);
}

// ---------------- dtype-robust index accessor ----------------
__device__ __forceinline__ int geti(const void* p, long long i, int f64) {
    return f64 ? (int)((const long long*)p)[i] : ((const int*)p)[i];
}

__global__ void k_detect(const void* ei, int* flag) {
    int t = threadIdx.x;
    const int* p = (const int*)ei;
    int acc = p[2 * t + 1] | p[2 * (t + 64) + 1];
    unsigned long long b = __ballot(acc != 0);
    if (t == 0) *flag = (b == 0ULL) ? 1 : 0;
}

// ---------------- weight prep: Wt[m][n][k] = bf16(W[m][k][n]) ----------------
__global__ void k_wprep(const float* __restrict__ W1, const float* __restrict__ W2,
                        unsigned short* __restrict__ Wt) {
    int m = blockIdx.y;
    int k = blockIdx.x;
    int n = threadIdx.x;
    const float* src = (m < NL) ? (W1 + (size_t)m * D * D) : (W2 + (size_t)(m - NL) * D * D);
    Wt[(size_t)m * D * D + n * D + k] = f2b(src[k * D + n]);
}

// ---------------- x -> bf16 mirror ----------------
__global__ void k_x2b(const float* __restrict__ x, unsigned short* __restrict__ xb) {
    int i = (blockIdx.x * 256 + threadIdx.x) * 4;
    float4 v = *(const float4*)&x[i];
    ushort4 b;
    b.x = f2b(v.x); b.y = f2b(v.y); b.z = f2b(v.z); b.w = f2b(v.w);
    *(ushort4*)&xb[i] = b;
}

// ---------------- CSR build: degree histogram ----------------
__global__ void k_hist(const void* ei, const int* __restrict__ flag, int* __restrict__ deg) {
    int e = blockIdx.x * 256 + threadIdx.x;
    int f = *flag;
    if (e < N_EDGES) {
        int d = geti(ei, (long long)N_EDGES + e, f);
        atomicAdd(&deg[d], 1);
    }
}

__global__ void k_scan1(const int* __restrict__ deg, int* __restrict__ bsum) {
    __shared__ int wsum[4];
    int tid = threadIdx.x;
    int base = blockIdx.x * 1024 + tid * 4;
    int s = 0;
#pragma unroll
    for (int j = 0; j < 4; ++j) {
        int idx = base + j;
        if (idx < N_NODES) s += deg[idx];
    }
    for (int off = 32; off > 0; off >>= 1) s += __shfl_down(s, off, 64);
    if ((tid & 63) == 0) wsum[tid >> 6] = s;
    __syncthreads();
    if (tid == 0) bsum[blockIdx.x] = wsum[0] + wsum[1] + wsum[2] + wsum[3];
}

__global__ void k_scan2(const int* __restrict__ bsum, int* __restrict__ boff,
                        int* __restrict__ rowp) {
    if (threadIdx.x == 0) {
        int run = 0;
        for (int b = 0; b < 98; ++b) {
            boff[b] = run;
            run += bsum[b];
        }
        rowp[N_NODES] = run;
    }
}

__global__ void k_scan3(const int* __restrict__ deg, const int* __restrict__ boff,
                        int* __restrict__ rowp) {
    __shared__ int wsum[4];
    int tid = threadIdx.x;
    int lane = tid & 63;
    int w = tid >> 6;
    int base = blockIdx.x * 1024 + tid * 4;
    int d[4];
    int tot = 0;
#pragma unroll
    for (int j = 0; j < 4; ++j) {
        int idx = base + j;
        d[j] = (idx < N_NODES) ? deg[idx] : 0;
        tot += d[j];
    }
    int incl = tot;
    for (int off = 1; off < 64; off <<= 1) {
        int v = __shfl_up(incl, off, 64);
        if (lane >= off) incl += v;
    }
    if (lane == 63) wsum[w] = incl;
    __syncthreads();
    int woff = boff[blockIdx.x];
    for (int w2 = 0; w2 < w; ++w2) woff += wsum[w2];
    int ex = woff + incl - tot;
#pragma unroll
    for (int j = 0; j < 4; ++j) {
        int idx = base + j;
        if (idx < N_NODES) rowp[idx] = ex;
        ex += d[j];
    }
}

// gcur[b] = rowp[b*BG]  (bucket write cursors for pass A)
__global__ void k_gcur(const int* __restrict__ rowp, int* __restrict__ gcur) {
    int b = blockIdx.x * 256 + threadIdx.x;
    if (b < NB) gcur[b] = rowp[min(b * BG, N_NODES)];
}

// ---- Pass A: partition edges into NB coarse dst-buckets, packed (dl<<17|src) ----
__global__ __launch_bounds__(256) void k_part(const void* ei, const int* __restrict__ flag,
                                              int* __restrict__ gcur,
                                              unsigned int* __restrict__ tmp) {
    __shared__ int hist[NB + 1];
    __shared__ int cur[NB + 1];
    int tid = threadIdx.x;
    long long e0 = (long long)blockIdx.x * EPB;
    int f = *flag;
    for (int b = tid; b < NB; b += 256) hist[b] = 0;
    __syncthreads();
    // phase 1: per-bucket count
    for (int i = 0; i < EPB / 256; ++i) {
        long long e = e0 + i * 256 + tid;
        if (e < N_EDGES) {
            int d = geti(ei, (long long)N_EDGES + e, f);
            atomicAdd(&hist[d / BG], 1);
        }
    }
    __syncthreads();
    // phase 2: reserve contiguous runs in each bucket's region
    for (int b = tid; b < NB; b += 256) {
        int h = hist[b];
        cur[b] = h ? atomicAdd(&gcur[b], h) : 0;
    }
    __syncthreads();
    // phase 3: write packed entries (contiguous per bucket per block)
    for (int i = 0; i < EPB / 256; ++i) {
        long long e = e0 + i * 256 + tid;
        if (e < N_EDGES) {
            int d = geti(ei, (long long)N_EDGES + e, f);
            int s = geti(ei, e, f);
            int b = d / BG;
            int pos = atomicAdd(&cur[b], 1);
            tmp[pos] = ((unsigned int)(d - b * BG) << 17) | (unsigned int)s;
        }
    }
}

// ---- Pass B: within-bucket scatter to exact CSR position (L2-local, merged) ----
__global__ __launch_bounds__(256) void k_fscat(const unsigned int* __restrict__ tmp,
                                               const int* __restrict__ rowp,
                                               int* __restrict__ eidx) {
    __shared__ int cur[BG];
    __shared__ int s_se[2];
    int b = blockIdx.x;
    int nb = b * BG;
    int nn = min(BG, N_NODES - nb);
    int tid = threadIdx.x;
    if (tid < nn) cur[tid] = rowp[nb + tid];
    if (tid == 0) s_se[0] = rowp[nb];
    if (tid == 1) s_se[1] = rowp[nb + nn];
    __syncthreads();
    for (int t = s_se[0] + tid; t < s_se[1]; t += 256) {
        unsigned int u = tmp[t];
        int dl = u >> 17;
        int pos = atomicAdd(&cur[dl], 1);
        eidx[pos] = (int)(u & 0x1FFFF);
    }
}

// ------------- aggregation (bf16 in / bf16 out, fp32 accumulate) -------------
// High-occupancy standalone gather: 8 VGPR, no LDS, one wave per node.
__global__ void k_aggb(const unsigned short* __restrict__ xb, const int* __restrict__ rowp,
                       const int* __restrict__ eidx, unsigned short* __restrict__ aggb) {
    int wid = threadIdx.x >> 6;
    int lane = threadIdx.x & 63;
    int node = blockIdx.x * 4 + wid;
    const unsigned int* x1 = (const unsigned int*)xb;   // 64 dwords per row
    unsigned int u = x1[(size_t)node * 64 + lane];
    float accx = __uint_as_float(u << 16);
    float accy = __uint_as_float(u & 0xffff0000u);
    int s = rowp[node], e = rowp[node + 1];
    int i = s;
    for (; i + 3 < e; i += 4) {
        unsigned int v0 = x1[(size_t)eidx[i] * 64 + lane];
        unsigned int v1 = x1[(size_t)eidx[i + 1] * 64 + lane];
        unsigned int v2 = x1[(size_t)eidx[i + 2] * 64 + lane];
        unsigned int v3 = x1[(size_t)eidx[i + 3] * 64 + lane];
        accx += __uint_as_float(v0 << 16) + __uint_as_float(v1 << 16);
        accy += __uint_as_float(v0 & 0xffff0000u) + __uint_as_float(v1 & 0xffff0000u);
        accx += __uint_as_float(v2 << 16) + __uint_as_float(v3 << 16);
        accy += __uint_as_float(v2 & 0xffff0000u) + __uint_as_float(v3 & 0xffff0000u);
    }
    for (; i < e; ++i) {
        unsigned int v0 = x1[(size_t)eidx[i] * 64 + lane];
        accx += __uint_as_float(v0 << 16);
        accy += __uint_as_float(v0 & 0xffff0000u);
    }
    unsigned int o = ((unsigned int)f2b(accy) << 16) | f2b(accx);
    ((unsigned int*)aggb)[(size_t)node * 64 + lane] = o;
}

// ---------------- MFMA GEMM: out = A @ W + bias (A, out bf16) ----------------
// MODE 1: A = agg (bf16); epilogue stores z bf16 + accumulates per-feature sum/sumsq
// MODE 2: A = z (bf16); A-load applies BN (scale/shift computed in-block from
//         stats/gamma/beta) + ReLU; epilogue ReLU, stores bf16.
template <int MODE>
__global__ __launch_bounds__(256) void k_lin(const unsigned short* __restrict__ A,
                                             const unsigned short* __restrict__ Wt,
                                             const float* __restrict__ bias,
                                             float* __restrict__ stats,
                                             const float* __restrict__ gamma,
                                             const float* __restrict__ beta,
                                             unsigned short* __restrict__ outb) {
    __shared__ unsigned short As[128 * 136];   // rows x 128k, stride 136
    __shared__ unsigned short Ws[128 * 136];   // n x 128k, stride 136
    __shared__ float red1[128];
    __shared__ float red2[128];

    int tid = threadIdx.x;
    int row0 = blockIdx.x * 128;

    if (MODE == 1 && tid < 128) {
        red1[tid] = 0.f;
        red2[tid] = 0.f;
    }
    if (MODE == 2 && tid < 128) {
        // recompute BN scale/shift from global stats (fused k_bnfin)
        float s1 = stats[tid];
        float s2 = stats[128 + tid];
        float mu = s1 / (float)N_NODES;
        float var = s2 / (float)N_NODES - mu * mu;
        float sc = rsqrtf(var + BN_EPS) * gamma[tid];
        red1[tid] = sc;               // scale
        red2[tid] = beta[tid] - mu * sc;  // shift
    }

    // stage Wt (full K=128) into LDS
#pragma unroll
    for (int i = 0; i < 8; ++i) {
        int chunk = tid + 256 * i;          // 0..2047
        int n = chunk >> 4;
        int k8 = (chunk & 15) * 8;
        *(bf16x8*)&Ws[n * 136 + k8] = *(const bf16x8*)&Wt[n * 128 + k8];
    }

    if (MODE == 2) __syncthreads();  // red1/red2 ready before A-stage uses them

    // stage A (full K=128) into LDS
#pragma unroll
    for (int i = 0; i < 8; ++i) {
        int chunk = tid + 256 * i;
        int row = chunk >> 4;
        int k8 = (chunk & 15) * 8;
        int gr = row0 + row;
        bf16x8 v = {0, 0, 0, 0, 0, 0, 0, 0};
        if (gr < N_NODES) v = *(const bf16x8*)&A[(size_t)gr * 128 + k8];
        if (MODE == 2) {
            bf16x8 o;
#pragma unroll
            for (int t = 0; t < 8; ++t) {
                float xv = b2f((unsigned short)v[t]);
                float z = fmaxf(xv * red1[k8 + t] + red2[k8 + t], 0.f);
                o[t] = (short)f2b(z);
            }
            v = o;
        }
        *(bf16x8*)&As[row * 136 + k8] = v;
    }
    __syncthreads();

    int w = tid >> 6, lane = tid & 63, q = lane >> 4, ln = lane & 15;
    int rbase = (w & 1) * 64, cbase = (w >> 1) * 64;

    f32x4 acc[4][4];
    f32x4 z4 = {0.f, 0.f, 0.f, 0.f};
#pragma unroll
    for (int rt = 0; rt < 4; ++rt)
#pragma unroll
        for (int ct = 0; ct < 4; ++ct) acc[rt][ct] = z4;

#pragma unroll
    for (int ks = 0; ks < 4; ++ks) {
        bf16x8 af[4], bfr[4];
#pragma unroll
        for (int rt = 0; rt < 4; ++rt)
            af[rt] = *(bf16x8*)&As[(rbase + rt * 16 + ln) * 136 + ks * 32 + q * 8];
#pragma unroll
        for (int ct = 0; ct < 4; ++ct)
            bfr[ct] = *(bf16x8*)&Ws[(cbase + ct * 16 + ln) * 136 + ks * 32 + q * 8];
#pragma unroll
        for (int rt = 0; rt < 4; ++rt)
#pragma unroll
            for (int ct = 0; ct < 4; ++ct)
                acc[rt][ct] = __builtin_amdgcn_mfma_f32_16x16x32_bf16(af[rt], bfr[ct],
                                                                      acc[rt][ct], 0, 0, 0);
    }

    if (MODE == 1) __syncthreads();  // re-init red1/red2 for stats reduction
    if (MODE == 1 && tid < 128) {
        red1[tid] = 0.f;
        red2[tid] = 0.f;
    }
    if (MODE == 1) __syncthreads();

    // epilogue
    float bsv[4], psum[4] = {0.f, 0.f, 0.f, 0.f}, psq[4] = {0.f, 0.f, 0.f, 0.f};
    int col[4];
#pragma unroll
    for (int ct = 0; ct < 4; ++ct) {
        col[ct] = cbase + ct * 16 + ln;
        bsv[ct] = bias[col[ct]];
    }
#pragma unroll
    for (int rt = 0; rt < 4; ++rt) {
        int gr0 = row0 + rbase + rt * 16 + q * 4;
#pragma unroll
        for (int i = 0; i < 4; ++i) {
            int gr = gr0 + i;
            if (gr < N_NODES) {
#pragma unroll
                for (int ct = 0; ct < 4; ++ct) {
                    float z = acc[rt][ct][i] + bsv[ct];
                    if (MODE == 2) {
                        z = fmaxf(z, 0.f);
                        outb[(size_t)gr * 128 + col[ct]] = f2b(z);
                    } else {
                        outb[(size_t)gr * 128 + col[ct]] = f2b(z);
                        psum[ct] += z;
                        psq[ct] += z * z;
                    }
                }
            }
        }
    }

    if (MODE == 1) {
#pragma unroll
        for (int ct = 0; ct < 4; ++ct) {
            atomicAdd(&red1[col[ct]], psum[ct]);
            atomicAdd(&red2[col[ct]], psq[ct]);
        }
        __syncthreads();
        if (tid < 128) {
            atomicAdd(&stats[tid], red1[tid]);
            atomicAdd(&stats[128 + tid], red2[tid]);
        }
    }
}

// ---------------- graph boundaries (batch is sorted) ----------------
__global__ void k_bounds(const void* batch, const int* __restrict__ flag,
                         int* __restrict__ starts) {
    int g = blockIdx.x * 256 + threadIdx.x;
    if (g > N_GRAPHS) return;
    int f = *flag;
    int lo = 0, hi = N_NODES;
    while (lo < hi) {
        int mid = (lo + hi) >> 1;
        if (geti(batch, mid, f) < g) lo = mid + 1;
        else hi = mid;
    }
    starts[g] = lo;
}

// ---------------- global add pool (bf16 in, fp32 out) ----------------
__global__ void k_pool(const unsigned short* __restrict__ xb, const int* __restrict__ starts,
                       float* __restrict__ gp) {
    int b = blockIdx.x, fi = threadIdx.x;
    int s = starts[b], e = starts[b + 1];
    float acc = 0.f;
    for (int i = s; i < e; ++i) acc += b2f(xb[(size_t)i * 128 + fi]);
    gp[(size_t)b * 128 + fi] = acc;
}

// ---------------- head MLP ----------------
__global__ void k_head(const float* __restrict__ gp, const float* __restrict__ fW1,
                       const float* __restrict__ fb1, const float* __restrict__ fW2,
                       const float* __restrict__ fb2, float* __restrict__ out) {
    __shared__ float gs[128];
    __shared__ float hs[128];
    int b = blockIdx.x, t = threadIdx.x;
    gs[t] = gp[(size_t)b * 128 + t];
    __syncthreads();
    float a = fb1[t];
    for (int k = 0; k < 128; ++k) a += gs[k] * fW1[k * 128 + t];
    hs[t] = fmaxf(a, 0.f);
    __syncthreads();
    if (t < 64) {
        float o = fb2[t];
        for (int k = 0; k < 128; ++k) o += hs[k] * fW2[k * 64 + t];
        out[(size_t)b * 64 + t] = o;
    }
}

extern "C" void kernel_launch(void* const* d_in, const int* in_sizes, int n_in,
                              void* d_out, int out_size, void* d_ws, size_t ws_size,
                              hipStream_t stream) {
    const float* x     = (const float*)d_in[0];
    const void*  ei    = d_in[1];
    const void*  batch = d_in[2];
    const float* W1    = (const float*)d_in[3];
    const float* b1    = (const float*)d_in[4];
    const float* gamma = (const float*)d_in[5];
    const float* beta  = (const float*)d_in[6];
    const float* W2    = (const float*)d_in[7];
    const float* b2    = (const float*)d_in[8];
    const float* fW1   = (const float*)d_in[9];
    const float* fb1   = (const float*)d_in[10];
    const float* fW2   = (const float*)d_in[11];
    const float* fb2   = (const float*)d_in[12];
    float* out = (float*)d_out;

    // workspace layout (all chunks multiple of 16 B)
    unsigned short* xb   = (unsigned short*)d_ws;                  // 12.8M us
    unsigned short* zb   = xb + (size_t)N_NODES * D;               // 12.8M us
    unsigned short* aggb = zb + (size_t)N_NODES * D;               // 12.8M us
    int* deg    = (int*)(aggb + (size_t)N_NODES * D);              // 100,000
    int* rowp   = deg + N_NODES;                                   // 100,004 (padded)
    int* eidx   = rowp + 100004;                                   // 1,600,000
    unsigned int* tmp = (unsigned int*)(eidx + N_EDGES);           // 1,600,000
    int* starts = (int*)(tmp + N_EDGES);                           // 1,028 (padded)
    int* dflag  = starts + 1028;                                   // 4
    int* bsum   = dflag + 4;                                       // 128
    int* boff   = bsum + 128;                                      // 128
    int* gcur   = boff + 128;                                      // 512
    float* stats = (float*)(gcur + 512);                           // 768
    float* gp    = stats + NL * 256;                               // 131,072
    unsigned short* Wt = (unsigned short*)(gp + (size_t)N_GRAPHS * D);  // 6*16384 us

    hipMemsetAsync(deg, 0, N_NODES * sizeof(int), stream);
    hipMemsetAsync(stats, 0, NL * 256 * sizeof(float), stream);

    k_detect<<<1, 64, 0, stream>>>(ei, dflag);
    k_wprep<<<dim3(128, 2 * NL), 128, 0, stream>>>(W1, W2, Wt);
    k_x2b<<<(N_NODES * D) / 1024, 256, 0, stream>>>(x, xb);
    k_hist<<<(N_EDGES + 255) / 256, 256, 0, stream>>>(ei, dflag, deg);
    k_scan1<<<98, 256, 0, stream>>>(deg, bsum);
    k_scan2<<<1, 64, 0, stream>>>(bsum, boff, rowp);
    k_scan3<<<98, 256, 0, stream>>>(deg, boff, rowp);
    k_gcur<<<2, 256, 0, stream>>>(rowp, gcur);
    k_part<<<(N_EDGES + EPB - 1) / EPB, 256, 0, stream>>>(ei, dflag, gcur, tmp);
    k_fscat<<<NB, 256, 0, stream>>>(tmp, rowp, eidx);

    const int gemm_grid = (N_NODES + 127) / 128;  // 782
    for (int l = 0; l < NL; ++l) {
        k_aggb<<<N_NODES / 4, 256, 0, stream>>>(xb, rowp, eidx, aggb);
        k_lin<1><<<gemm_grid, 256, 0, stream>>>(
            aggb, Wt + (size_t)l * D * D, b1 + (size_t)l * D,
            stats + (size_t)l * 256, nullptr, nullptr, zb);
        k_lin<2><<<gemm_grid, 256, 0, stream>>>(
            zb, Wt + (size_t)(NL + l) * D * D, b2 + (size_t)l * D,
            stats + (size_t)l * 256, gamma + (size_t)l * D, beta + (size_t)l * D, xb);
    }

    k_bounds<<<5, 256, 0, stream>>>(batch, dflag, starts);
    k_pool<<<N_GRAPHS, 128, 0, stream>>>(xb, starts, gp);
    k_head<<<N_GRAPHS, 128, 0, stream>>>(gp, fW1, fb1, fW2, fb2, out);
}